// Round 1
// baseline (638.563 us; speedup 1.0000x reference)
//
#include <hip/hip_runtime.h>

#define BATCH   8
#define HW      21760        // 128^2 + 64^2 + 32^2 + 16^2
#define NCLS    80
#define NCH     85           // NCLS + 5
#define TOPK    100
#define CAP     8192         // per-batch candidate capacity
#define NBIN    8192
#define BINSHIFT 19          // float bits >> 19 -> 8 exp + 4 mantissa bits
#define TILES   340          // HW / 64
#define NB      128          // blocks per batch for stencil kernels

__device__ __forceinline__ float sigmoidf_(float x) { return 1.0f / (1.0f + expf(-x)); }

// ---------------- stage 1: powered class scores, layout S[b][c][hw] ----------------
__global__ void k_scores(const float* __restrict__ pred, float* __restrict__ S) {
    int blk = blockIdx.x;
    int b = blk / TILES, tile = blk - b * TILES;
    int hw0 = tile * 64;
    __shared__ float t85[64 * NCH];
    __shared__ float esh[64];
    const float* src = pred + ((size_t)(b * HW + hw0)) * NCH;
    for (int t = threadIdx.x; t < 64 * NCH; t += 256) t85[t] = src[t];
    __syncthreads();
    if (threadIdx.x < 64) {
        float s1 = sigmoidf_(t85[threadIdx.x * NCH + (NCH - 1)]);
        float n2 = 1.0f / (1.0f + expf(1.0f - 2.0f * s1));
        esh[threadIdx.x] = (2.0f - n2) * 0.6f + 1e-14f;
    }
    __syncthreads();
    for (int t = threadIdx.x; t < 64 * NCLS; t += 256) {
        int row = t & 63, c = t >> 6;
        float p = sigmoidf_(t85[row * NCH + c]);
        S[((size_t)(b * NCLS + c)) * HW + hw0 + row] = powf(p, esh[row]);
    }
}

// survivor test: v is max of its 3x3 (cls, flat-hw) neighborhood (clamped edges)
__device__ __forceinline__ bool is_peak(const float* __restrict__ s, int c, int hw, float v) {
    int c0 = c > 0 ? c - 1 : 0, c1 = c < NCLS - 1 ? c + 1 : NCLS - 1;
    int h0 = hw > 0 ? hw - 1 : 0, h1 = hw < HW - 1 ? hw + 1 : HW - 1;
    for (int cc = c0; cc <= c1; ++cc)
        for (int hh = h0; hh <= h1; ++hh)
            if (s[(size_t)cc * HW + hh] > v) return false;
    return true;
}

// ---------------- stage 2: per-batch survivor-value histogram ----------------
__global__ void k_hist(const float* __restrict__ S, unsigned int* __restrict__ ghist) {
    __shared__ unsigned int h[NBIN];
    for (int i = threadIdx.x; i < NBIN; i += 256) h[i] = 0;
    __syncthreads();
    int bb = blockIdx.x;
    int b = bb >> 7;            // NB = 128
    int bib = bb & (NB - 1);
    const float* s = S + (size_t)b * NCLS * HW;
    const int TOT = NCLS * HW;
    for (int l = bib * 256 + threadIdx.x; l < TOT; l += NB * 256) {
        int c = l / HW, hw = l - c * HW;
        float v = s[l];
        if (is_peak(s, c, hw, v)) atomicAdd(&h[__float_as_uint(v) >> BINSHIFT], 1u);
    }
    __syncthreads();
    for (int i = threadIdx.x; i < NBIN; i += 256)
        if (h[i]) atomicAdd(&ghist[b * NBIN + i], h[i]);
}

// ---------------- stage 3: find rank-TOPK threshold (lower edge of boundary bin) ----------------
__global__ void k_thresh(const unsigned int* __restrict__ ghist, unsigned int* __restrict__ tbits) {
    int b = blockIdx.x;
    const unsigned int* h = ghist + b * NBIN;
    __shared__ unsigned int part[256];
    int t = threadIdx.x;
    int hi = NBIN - 1 - 32 * t;
    unsigned int sum = 0;
    for (int i = 0; i < 32; ++i) sum += h[hi - i];
    part[t] = sum;
    __syncthreads();
    if (t == 0) {
        unsigned int cum = 0, thr = 0;
        for (int k = 0; k < 256; ++k) {
            if (cum + part[k] >= TOPK) {
                int hik = NBIN - 1 - 32 * k;
                for (int bin = hik; bin > hik - 32; --bin) {
                    cum += h[bin];
                    if (cum >= TOPK) { thr = (unsigned int)bin; break; }
                }
                break;
            }
            cum += part[k];
        }
        tbits[b] = thr << BINSHIFT;
    }
}

// ---------------- stage 4: compact candidates >= threshold ----------------
__global__ void k_compact(const float* __restrict__ S, const unsigned int* __restrict__ tbits,
                          float* __restrict__ cval, int* __restrict__ cidx,
                          unsigned int* __restrict__ ccnt) {
    int bb = blockIdx.x;
    int b = bb >> 7;
    int bib = bb & (NB - 1);
    const float* s = S + (size_t)b * NCLS * HW;
    unsigned int thr = tbits[b];
    const int TOT = NCLS * HW;
    for (int l = bib * 256 + threadIdx.x; l < TOT; l += NB * 256) {
        float v = s[l];
        if (__float_as_uint(v) >= thr) {
            int c = l / HW, hw = l - c * HW;
            if (is_peak(s, c, hw, v)) {
                unsigned int pos = atomicAdd(&ccnt[b], 1u);
                if (pos < CAP) { cval[b * CAP + pos] = v; cidx[b * CAP + pos] = l; }
            }
        }
    }
}

// ---------------- stage 5: per-batch exact top-100 + box decode + greedy NMS + outputs ----------------
__global__ void k_final(const float* __restrict__ pred, const float* __restrict__ pix,
                        const float* __restrict__ cval, const int* __restrict__ cidx,
                        const unsigned int* __restrict__ ccnt, float* __restrict__ out) {
    int b = blockIdx.x;
    int cnt = (int)min(ccnt[b], (unsigned int)CAP);
    const float* v = cval + b * CAP;
    const int* ix = cidx + b * CAP;

    __shared__ float tv[TOPK];
    __shared__ int   ti[TOPK];
    __shared__ float rv[256];
    __shared__ int   ri[256];
    __shared__ int   rs[256];
    __shared__ unsigned int used[CAP / 32];
    for (int i = threadIdx.x; i < CAP / 32; i += 256) used[i] = 0;
    __syncthreads();

    // exact top-100: value desc, flat-index asc tie-break (matches top_k stability)
    for (int r = 0; r < TOPK; ++r) {
        float bv = -1.0f; int bi = 0x7fffffff; int bs = -1;
        for (int k = threadIdx.x; k < cnt; k += 256) {
            if (used[k >> 5] & (1u << (k & 31))) continue;
            float vv = v[k]; int ii = ix[k];
            if (vv > bv || (vv == bv && ii < bi)) { bv = vv; bi = ii; bs = k; }
        }
        rv[threadIdx.x] = bv; ri[threadIdx.x] = bi; rs[threadIdx.x] = bs;
        __syncthreads();
        for (int st = 128; st > 0; st >>= 1) {
            if (threadIdx.x < st) {
                float ov = rv[threadIdx.x + st]; int oi = ri[threadIdx.x + st];
                if (ov > rv[threadIdx.x] || (ov == rv[threadIdx.x] && oi < ri[threadIdx.x])) {
                    rv[threadIdx.x] = ov; ri[threadIdx.x] = oi; rs[threadIdx.x] = rs[threadIdx.x + st];
                }
            }
            __syncthreads();
        }
        if (threadIdx.x == 0) {
            if (rs[0] >= 0) { tv[r] = rv[0]; ti[r] = ri[0]; used[rs[0] >> 5] |= 1u << (rs[0] & 31); }
            else            { tv[r] = 0.0f; ti[r] = 0; }
        }
        __syncthreads();
    }

    // decode boxes
    __shared__ float x1s[TOPK], y1s[TOPK], x2s[TOPK], y2s[TOPK], ar[TOPK];
    __shared__ int cls[TOPK];
    __shared__ unsigned char sup[TOPK], keep[TOPK], val[TOPK];
    if (threadIdx.x < TOPK) {
        int k = threadIdx.x;
        int idx = ti[k];
        int c = idx / HW, hw = idx - c * HW;
        const float* p = pred + ((size_t)(b * HW + hw)) * NCH + NCLS;
        float a0 = fmaxf(p[0], 0.0f), a1 = fmaxf(p[1], 0.0f);
        float a2 = fmaxf(p[2], 0.0f), a3 = fmaxf(p[3], 0.0f);
        float px = pix[hw * 4 + 0], py = pix[hw * 4 + 1];
        float X1 = px - a0, Y1 = py - a1, X2 = px + a2, Y2 = py + a3;
        x1s[k] = X1; y1s[k] = Y1; x2s[k] = X2; y2s[k] = Y2;
        ar[k] = (X2 - X1) * (Y2 - Y1);
        cls[k] = c; sup[k] = 0; keep[k] = 0;
        val[k] = (tv[k] > 0.05f) ? 1 : 0;
    }
    __syncthreads();

    // greedy NMS (sort order == input order; see idempotence/prefix argument)
    for (int i = 0; i < TOPK; ++i) {
        bool ki = (val[i] != 0) && (sup[i] == 0);
        if (threadIdx.x == i) keep[i] = ki ? 1 : 0;
        if (ki && threadIdx.x < TOPK) {
            int k = threadIdx.x;
            if (k > i && cls[k] == cls[i]) {
                float xx1 = fmaxf(x1s[i], x1s[k]), yy1 = fmaxf(y1s[i], y1s[k]);
                float xx2 = fminf(x2s[i], x2s[k]), yy2 = fminf(y2s[i], y2s[k]);
                float w = fmaxf(1e-28f, xx2 - xx1), h = fmaxf(1e-28f, yy2 - yy1);
                float inter = w * h;
                float ovr = inter / (ar[i] + ar[k] - inter);
                if (ovr > 0.5f) sup[k] = 1;
            }
        }
        __syncthreads();
    }

    // outputs: bboxes(3200) | scores(800) | cls(800) | keep(800)
    if (threadIdx.x < TOPK) {
        int k = threadIdx.x;
        const float inv = 1.0f / 512.0f;
        float b0 = fminf(fmaxf(x1s[k] * inv, 0.0f), 1.0f);
        float b1 = fminf(fmaxf(y1s[k] * inv, 0.0f), 1.0f);
        float b2 = fminf(fmaxf(x2s[k] * inv, 0.0f), 1.0f);
        float b3 = fminf(fmaxf(y2s[k] * inv, 0.0f), 1.0f);
        size_t o = (size_t)b * TOPK + k;
        out[o * 4 + 0] = b0; out[o * 4 + 1] = b1;
        out[o * 4 + 2] = b2; out[o * 4 + 3] = b3;
        out[(size_t)BATCH * TOPK * 4 + o] = tv[k];
        out[(size_t)BATCH * TOPK * 5 + o] = (float)cls[k];
        out[(size_t)BATCH * TOPK * 6 + o] = keep[k] ? 1.0f : 0.0f;
    }
}

extern "C" void kernel_launch(void* const* d_in, const int* in_sizes, int n_in,
                              void* d_out, int out_size, void* d_ws, size_t ws_size,
                              hipStream_t stream) {
    const float* pred = (const float*)d_in[0];       // (8, 21760, 85)
    const float* pix  = (const float*)d_in[1];       // (21760, 4)
    float* out = (float*)d_out;                      // 5600 floats

    char* ws = (char*)d_ws;
    size_t off = 0;
    float* S = (float*)(ws + off);            off += (size_t)BATCH * NCLS * HW * sizeof(float);
    unsigned int* ghist = (unsigned int*)(ws + off); off += (size_t)BATCH * NBIN * sizeof(unsigned int);
    unsigned int* tbits = (unsigned int*)(ws + off); off += BATCH * sizeof(unsigned int);
    unsigned int* ccnt  = (unsigned int*)(ws + off); off += BATCH * sizeof(unsigned int);
    float* cval = (float*)(ws + off);         off += (size_t)BATCH * CAP * sizeof(float);
    int*   cidx = (int*)(ws + off);           off += (size_t)BATCH * CAP * sizeof(int);

    // zero hist + tbits + ccnt (contiguous region right after S)
    hipMemsetAsync(ghist, 0, (size_t)(BATCH * NBIN + 2 * BATCH) * sizeof(unsigned int), stream);

    k_scores <<<BATCH * TILES, 256, 0, stream>>>(pred, S);
    k_hist   <<<BATCH * NB,    256, 0, stream>>>(S, ghist);
    k_thresh <<<BATCH,         256, 0, stream>>>(ghist, tbits);
    k_compact<<<BATCH * NB,    256, 0, stream>>>(S, tbits, cval, cidx, ccnt);
    k_final  <<<BATCH,         256, 0, stream>>>(pred, pix, cval, cidx, ccnt, out);
}